// Round 8
// baseline (393.493 us; speedup 1.0000x reference)
//
#include <hip/hip_runtime.h>
#include <math.h>

// PathPreservingNetwork — factored-class + bf16x3 MFMA, R8.
// Classes per layer input: 1,1,3,7,15,31; every path value is s*C[class].
// R8: big layers (L3/L4/L5) move to 128x128 block tiles with 64x64 wave tiles
// (4x4 16-tiles, 48 MFMA per 16 ds_read_b128 per wave-slab — halves the LDS
// bytes/flop that bound the 64x64 kernel). Flat workspace (ws = 256 MiB per
// harness fill counters) — no lifetime aliasing. L0-L2 keep the proven R7
// 64x64 split-K path. 14 launches.

using s8v = __attribute__((ext_vector_type(8))) short;
using f4v = __attribute__((ext_vector_type(4))) float;

__device__ __forceinline__ float bf2f(short b) {
  unsigned u = ((unsigned)(unsigned short)b) << 16;
  return __builtin_bit_cast(float, u);
}
__device__ __forceinline__ short f2bf(float f) {
  unsigned u = __builtin_bit_cast(unsigned, f);
  u = (u + 0x7FFFu + ((u >> 16) & 1u)) >> 16;
  return (short)u;
}

// Transpose+split all six W -> (N x 1024 bf16 hi/lo). z==6: blocks 0..127
// pack x (fp32 -> hi/lo); blocks 128..175 zero the ns/dotv/nrmv zone.
struct TWArgs {
  const float* W[6];
  short* Th[6];
  short* Tl[6];
  const float* x;
  short* A0h;
  short* A0l;
  float* zone;  // 12288 floats: ns(3968) dotv(3968) nrmv(3968) + pad
};
__global__ void __launch_bounds__(256)
transW_all(TWArgs a) {
  const int z = blockIdx.z;
  const int t = threadIdx.x;
  if (z == 6) {
    int bid = blockIdx.y * 16 + blockIdx.x;
    if (bid < 128) {
      int i = (bid * 256 + t) * 4;
      float4 v = *(const float4*)&a.x[i];
      short4 h, l;
      h.x = f2bf(v.x); l.x = f2bf(v.x - bf2f(h.x));
      h.y = f2bf(v.y); l.y = f2bf(v.y - bf2f(h.y));
      h.z = f2bf(v.z); l.z = f2bf(v.z - bf2f(h.z));
      h.w = f2bf(v.w); l.w = f2bf(v.w - bf2f(h.w));
      *(short4*)&a.A0h[i] = h;
      *(short4*)&a.A0l[i] = l;
    } else if (bid < 176) {
      a.zone[(bid - 128) * 256 + t] = 0.f;
    }
    return;
  }
  const int N = (z == 5) ? 512 : 1024;
  const int n0 = blockIdx.x * 64, k0 = blockIdx.y * 64;
  if (n0 >= N) return;
  const float* __restrict__ W = a.W[z];
  short* __restrict__ Th = a.Th[z];
  short* __restrict__ Tl = a.Tl[z];
  __shared__ float tile[64][65];
  const int r = t >> 4, c4 = (t & 15) * 4;
#pragma unroll
  for (int i = 0; i < 4; ++i) {
    int rr = r + 16 * i;
    float4 v = *(const float4*)&W[(size_t)(k0 + rr) * N + n0 + c4];
    tile[rr][c4 + 0] = v.x;
    tile[rr][c4 + 1] = v.y;
    tile[rr][c4 + 2] = v.z;
    tile[rr][c4 + 3] = v.w;
  }
  __syncthreads();
#pragma unroll
  for (int i = 0; i < 4; ++i) {
    int n = r + 16 * i;
    short4 h, l;
    float f0 = tile[c4 + 0][n], f1 = tile[c4 + 1][n];
    float f2 = tile[c4 + 2][n], f3 = tile[c4 + 3][n];
    h.x = f2bf(f0); l.x = f2bf(f0 - bf2f(h.x));
    h.y = f2bf(f1); l.y = f2bf(f1 - bf2f(h.y));
    h.z = f2bf(f2); l.z = f2bf(f2 - bf2f(h.z));
    h.w = f2bf(f3); l.w = f2bf(f3 - bf2f(h.w));
    size_t o = (size_t)(n0 + n) * 1024 + k0 + c4;
    *(short4*)&Th[o] = h;
    *(short4*)&Tl[o] = l;
  }
}

// ------------------------------------------------- small MFMA GEMM (64x64) --
// Split-K partial only (L0-L2). Proven R7 structure.
template <int KS>
__global__ void __launch_bounds__(256, 3)
mfma_gemm_s(const short* __restrict__ Ah, const short* __restrict__ Al,
            const short* __restrict__ Bh, const short* __restrict__ Bl,
            float* __restrict__ Of, int N) {
  constexpr int KC = 1024 / KS;
  constexpr int BKP = 40;
  __shared__ short As_h[64 * BKP], As_l[64 * BKP];
  __shared__ short Bs_h[64 * BKP], Bs_l[64 * BKP];
  __shared__ float et[64][68];
  const int t = threadIdx.x;
  const int row0 = blockIdx.y * 64;
  const int col0 = blockIdx.x * 64;
  const int kb = blockIdx.z * KC;
  const int sr = t >> 2, sko = (t & 3) * 8;
  const short* Ahp = Ah + (size_t)(row0 + sr) * 1024 + kb + sko;
  const short* Alp = Al + (size_t)(row0 + sr) * 1024 + kb + sko;
  const short* Bhp = Bh + (size_t)(col0 + sr) * 1024 + kb + sko;
  const short* Blp = Bl + (size_t)(col0 + sr) * 1024 + kb + sko;
  const int w = t >> 6, lane = t & 63;
  const int l16 = lane & 15, q = lane >> 4;
  const int wm0 = (w & 1) * 32, wn0 = (w >> 1) * 32;
  const int abase = (wm0 + l16) * BKP + q * 8;
  const int bbase = (wn0 + l16) * BKP + q * 8;
  f4v acc[2][2];
#pragma unroll
  for (int i = 0; i < 2; ++i)
#pragma unroll
    for (int j = 0; j < 2; ++j) acc[i][j] = (f4v){0.f, 0.f, 0.f, 0.f};
  uint4 rah = *(const uint4*)(Ahp);
  uint4 ral = *(const uint4*)(Alp);
  uint4 rbh = *(const uint4*)(Bhp);
  uint4 rbl = *(const uint4*)(Blp);
  for (int k0 = 0; k0 < KC; k0 += 32) {
    __syncthreads();
    *(uint4*)&As_h[sr * BKP + sko] = rah;
    *(uint4*)&As_l[sr * BKP + sko] = ral;
    *(uint4*)&Bs_h[sr * BKP + sko] = rbh;
    *(uint4*)&Bs_l[sr * BKP + sko] = rbl;
    if (k0 + 32 < KC) {
      rah = *(const uint4*)(Ahp + k0 + 32);
      ral = *(const uint4*)(Alp + k0 + 32);
      rbh = *(const uint4*)(Bhp + k0 + 32);
      rbl = *(const uint4*)(Blp + k0 + 32);
    }
    __syncthreads();
    s8v ah[2], al[2], bh[2], bl[2];
#pragma unroll
    for (int mt = 0; mt < 2; ++mt) {
      ah[mt] = *(const s8v*)&As_h[abase + mt * 16 * BKP];
      al[mt] = *(const s8v*)&As_l[abase + mt * 16 * BKP];
    }
#pragma unroll
    for (int nt = 0; nt < 2; ++nt) {
      bh[nt] = *(const s8v*)&Bs_h[bbase + nt * 16 * BKP];
      bl[nt] = *(const s8v*)&Bs_l[bbase + nt * 16 * BKP];
    }
#pragma unroll
    for (int mt = 0; mt < 2; ++mt)
#pragma unroll
      for (int nt = 0; nt < 2; ++nt) {
        acc[mt][nt] = __builtin_amdgcn_mfma_f32_16x16x32_bf16(
            ah[mt], bh[nt], acc[mt][nt], 0, 0, 0);
        acc[mt][nt] = __builtin_amdgcn_mfma_f32_16x16x32_bf16(
            ah[mt], bl[nt], acc[mt][nt], 0, 0, 0);
        acc[mt][nt] = __builtin_amdgcn_mfma_f32_16x16x32_bf16(
            al[mt], bh[nt], acc[mt][nt], 0, 0, 0);
      }
  }
#pragma unroll
  for (int mt = 0; mt < 2; ++mt)
#pragma unroll
    for (int nt = 0; nt < 2; ++nt)
#pragma unroll
      for (int r = 0; r < 4; ++r)
        et[wm0 + mt * 16 + q * 4 + r][wn0 + nt * 16 + l16] = acc[mt][nt][r];
  __syncthreads();
  const int rl = t >> 2, cc = (t & 3) * 16;
  float v[16];
#pragma unroll
  for (int j = 0; j < 16; ++j) v[j] = et[rl][cc + j];
  const int rr = row0 + rl;
  const int R = (int)gridDim.y << 6;
  float* dst = Of + ((size_t)blockIdx.z * R + rr) * N + col0 + cc;
#pragma unroll
  for (int i = 0; i < 4; ++i)
    *(float4*)&dst[4 * i] =
        make_float4(v[4 * i], v[4 * i + 1], v[4 * i + 2], v[4 * i + 3]);
}

// --------------------------------------------------- big MFMA GEMM (128x128)-
// 4 waves 2x2, 64x64 per wave (4x4 16-tiles): 48 MFMA / 16 ds_read_b128 per
// wave-slab. Staging LDS (40 KB) overlaid with the 64x132 epilogue transpose
// tile. Two-pass coalesced epilogue.
// EPI 0: split-K partial -> P[(bz*R + rr)*N + col]   (fp32, float4 stores)
// EPI 1: L4 — rows b*31+1+2u / +2+2u = tanh(bias -/+ acc) hi/lo + zero row at
//         u==0; fused per-row sumsq atomics into ns.
// EPI 2: L5 — raw fp32 out + fused ||Y||^2 / dot(b5,Y) atomics.
template <int EPI, int D, int KS>
__global__ void __launch_bounds__(256, 2)
mfma_gemm_b(const short* __restrict__ Ah, const short* __restrict__ Al,
            const short* __restrict__ Bh, const short* __restrict__ Bl,
            const float* __restrict__ bias, short* __restrict__ Oh,
            short* __restrict__ Ol, float* __restrict__ Of,
            float* __restrict__ ns, float* __restrict__ dotv,
            float* __restrict__ nrmv, int N, int Dn) {
  constexpr int KC = 1024 / KS;
  constexpr int BKP = 40;
  __shared__ short smem[4 * 128 * BKP];  // 40960 B; overlaid by et (33792 B)
  short* As_h = smem;
  short* As_l = smem + 128 * BKP;
  short* Bs_h = smem + 2 * 128 * BKP;
  short* Bs_l = smem + 3 * 128 * BKP;
  float* et = (float*)smem;  // [64][132]
  __shared__ float bias_s[128];
  const int t = threadIdx.x;
  const int row0 = blockIdx.y * 128;
  const int col0 = blockIdx.x * 128;
  const int kb = blockIdx.z * KC;
  if (EPI >= 1 && t < 32)
    *(float4*)&bias_s[t * 4] = *(const float4*)&bias[col0 + t * 4];
  const int sr = t >> 1, sko = (t & 1) * 16;
  const short* Ahp = Ah + (size_t)(row0 + sr) * 1024 + kb + sko;
  const short* Alp = Al + (size_t)(row0 + sr) * 1024 + kb + sko;
  const short* Bhp = Bh + (size_t)(col0 + sr) * 1024 + kb + sko;
  const short* Blp = Bl + (size_t)(col0 + sr) * 1024 + kb + sko;
  const int w = t >> 6, lane = t & 63;
  const int l16 = lane & 15, q = lane >> 4;
  const int wm0 = (w & 1) * 64, wn0 = (w >> 1) * 64;
  f4v acc[4][4];
#pragma unroll
  for (int i = 0; i < 4; ++i)
#pragma unroll
    for (int j = 0; j < 4; ++j) acc[i][j] = (f4v){0.f, 0.f, 0.f, 0.f};
  uint4 rah[2], ral[2], rbh[2], rbl[2];
#pragma unroll
  for (int j = 0; j < 2; ++j) {
    rah[j] = *(const uint4*)(Ahp + 8 * j);
    ral[j] = *(const uint4*)(Alp + 8 * j);
    rbh[j] = *(const uint4*)(Bhp + 8 * j);
    rbl[j] = *(const uint4*)(Blp + 8 * j);
  }
  for (int k0 = 0; k0 < KC; k0 += 32) {
    __syncthreads();
#pragma unroll
    for (int j = 0; j < 2; ++j) {
      *(uint4*)&As_h[sr * BKP + sko + 8 * j] = rah[j];
      *(uint4*)&As_l[sr * BKP + sko + 8 * j] = ral[j];
      *(uint4*)&Bs_h[sr * BKP + sko + 8 * j] = rbh[j];
      *(uint4*)&Bs_l[sr * BKP + sko + 8 * j] = rbl[j];
    }
    if (k0 + 32 < KC) {
#pragma unroll
      for (int j = 0; j < 2; ++j) {
        rah[j] = *(const uint4*)(Ahp + k0 + 32 + 8 * j);
        ral[j] = *(const uint4*)(Alp + k0 + 32 + 8 * j);
        rbh[j] = *(const uint4*)(Bhp + k0 + 32 + 8 * j);
        rbl[j] = *(const uint4*)(Blp + k0 + 32 + 8 * j);
      }
    }
    __syncthreads();
    s8v ah[4], al[4], bh[4], bl[4];
#pragma unroll
    for (int mt = 0; mt < 4; ++mt) {
      int o = (wm0 + mt * 16 + l16) * BKP + q * 8;
      ah[mt] = *(const s8v*)&As_h[o];
      al[mt] = *(const s8v*)&As_l[o];
    }
#pragma unroll
    for (int nt = 0; nt < 4; ++nt) {
      int o = (wn0 + nt * 16 + l16) * BKP + q * 8;
      bh[nt] = *(const s8v*)&Bs_h[o];
      bl[nt] = *(const s8v*)&Bs_l[o];
    }
#pragma unroll
    for (int mt = 0; mt < 4; ++mt)
#pragma unroll
      for (int nt = 0; nt < 4; ++nt) {
        acc[mt][nt] = __builtin_amdgcn_mfma_f32_16x16x32_bf16(
            ah[mt], bh[nt], acc[mt][nt], 0, 0, 0);
        acc[mt][nt] = __builtin_amdgcn_mfma_f32_16x16x32_bf16(
            ah[mt], bl[nt], acc[mt][nt], 0, 0, 0);
        acc[mt][nt] = __builtin_amdgcn_mfma_f32_16x16x32_bf16(
            al[mt], bh[nt], acc[mt][nt], 0, 0, 0);
      }
  }

  // Two-pass epilogue through the overlaid transpose tile (rows 0..63, 64..127)
  const int rl = t >> 2, cc4 = (t & 3) * 32;
  for (int pp = 0; pp < 2; ++pp) {
    __syncthreads();  // staging reads (pass 0) / et reads (pass 1) complete
    if ((w & 1) == pp) {
#pragma unroll
      for (int mt = 0; mt < 4; ++mt)
#pragma unroll
        for (int nt = 0; nt < 4; ++nt)
#pragma unroll
          for (int r = 0; r < 4; ++r)
            et[(mt * 16 + q * 4 + r) * 132 + wn0 + nt * 16 + l16] =
                acc[mt][nt][r];
    }
    __syncthreads();
    float v[32];
#pragma unroll
    for (int j = 0; j < 32; ++j) v[j] = et[rl * 132 + cc4 + j];
    const int rr = row0 + pp * 64 + rl;

    if constexpr (EPI == 0) {
      const int R = (int)gridDim.y << 7;
      float* dst = Of + ((size_t)blockIdx.z * R + rr) * N + col0 + cc4;
#pragma unroll
      for (int i = 0; i < 8; ++i)
        *(float4*)&dst[4 * i] =
            make_float4(v[4 * i], v[4 * i + 1], v[4 * i + 2], v[4 * i + 3]);
    } else if constexpr (EPI == 1) {
      const int b = rr / D, u = rr - b * D;
      const size_t ob = (size_t)(b * Dn) * (size_t)N + col0 + cc4;
      const size_t om = ob + (size_t)(1 + 2 * u) * N;
      const size_t op = ob + (size_t)(2 + 2 * u) * N;
      uint mh[16], ml[16], qh[16], ql[16];
      float sm = 0.f, sp = 0.f;
#pragma unroll
      for (int j2 = 0; j2 < 16; ++j2) {
        float bc0 = bias_s[cc4 + 2 * j2];
        float bc1 = bias_s[cc4 + 2 * j2 + 1];
        float tm0 = tanhf(bc0 - v[2 * j2]), tm1 = tanhf(bc1 - v[2 * j2 + 1]);
        float tp0 = tanhf(bc0 + v[2 * j2]), tp1 = tanhf(bc1 + v[2 * j2 + 1]);
        short h0 = f2bf(tm0), h1 = f2bf(tm1);
        short g0 = f2bf(tm0 - bf2f(h0)), g1 = f2bf(tm1 - bf2f(h1));
        mh[j2] = (uint)(unsigned short)h0 | ((uint)(unsigned short)h1 << 16);
        ml[j2] = (uint)(unsigned short)g0 | ((uint)(unsigned short)g1 << 16);
        h0 = f2bf(tp0); h1 = f2bf(tp1);
        g0 = f2bf(tp0 - bf2f(h0)); g1 = f2bf(tp1 - bf2f(h1));
        qh[j2] = (uint)(unsigned short)h0 | ((uint)(unsigned short)h1 << 16);
        ql[j2] = (uint)(unsigned short)g0 | ((uint)(unsigned short)g1 << 16);
        sm = fmaf(tm0, tm0, fmaf(tm1, tm1, sm));
        sp = fmaf(tp0, tp0, fmaf(tp1, tp1, sp));
      }
#pragma unroll
      for (int i = 0; i < 4; ++i) {
        *(uint4*)&Oh[om + 8 * i] =
            make_uint4(mh[4 * i], mh[4 * i + 1], mh[4 * i + 2], mh[4 * i + 3]);
        *(uint4*)&Ol[om + 8 * i] =
            make_uint4(ml[4 * i], ml[4 * i + 1], ml[4 * i + 2], ml[4 * i + 3]);
        *(uint4*)&Oh[op + 8 * i] =
            make_uint4(qh[4 * i], qh[4 * i + 1], qh[4 * i + 2], qh[4 * i + 3]);
        *(uint4*)&Ol[op + 8 * i] =
            make_uint4(ql[4 * i], ql[4 * i + 1], ql[4 * i + 2], ql[4 * i + 3]);
      }
      sm += __shfl_xor(sm, 1); sm += __shfl_xor(sm, 2);
      sp += __shfl_xor(sp, 1); sp += __shfl_xor(sp, 2);
      if ((t & 3) == 0) {
        atomicAdd(&ns[b * Dn + 1 + 2 * u], sm);
        atomicAdd(&ns[b * Dn + 2 + 2 * u], sp);
      }
      if (u == 0) {
        float sz = 0.f;
        uint zh[16], zl[16];
#pragma unroll
        for (int j2 = 0; j2 < 16; ++j2) {
          float tz0 = tanhf(bias_s[cc4 + 2 * j2]);
          float tz1 = tanhf(bias_s[cc4 + 2 * j2 + 1]);
          short h0 = f2bf(tz0), h1 = f2bf(tz1);
          short g0 = f2bf(tz0 - bf2f(h0)), g1 = f2bf(tz1 - bf2f(h1));
          zh[j2] = (uint)(unsigned short)h0 | ((uint)(unsigned short)h1 << 16);
          zl[j2] = (uint)(unsigned short)g0 | ((uint)(unsigned short)g1 << 16);
          sz = fmaf(tz0, tz0, fmaf(tz1, tz1, sz));
        }
#pragma unroll
        for (int i = 0; i < 4; ++i) {
          *(uint4*)&Oh[ob + 8 * i] = make_uint4(zh[4 * i], zh[4 * i + 1],
                                                zh[4 * i + 2], zh[4 * i + 3]);
          *(uint4*)&Ol[ob + 8 * i] = make_uint4(zl[4 * i], zl[4 * i + 1],
                                                zl[4 * i + 2], zl[4 * i + 3]);
        }
        sz += __shfl_xor(sz, 1); sz += __shfl_xor(sz, 2);
        if ((t & 3) == 0) atomicAdd(&ns[b * Dn], sz);
      }
    } else {
      float nr = 0.f, dt = 0.f;
      float* dst = Of + (size_t)rr * N + col0 + cc4;
#pragma unroll
      for (int j = 0; j < 32; ++j) {
        nr = fmaf(v[j], v[j], nr);
        dt = fmaf(v[j], bias_s[cc4 + j], dt);
      }
#pragma unroll
      for (int i = 0; i < 8; ++i)
        *(float4*)&dst[4 * i] =
            make_float4(v[4 * i], v[4 * i + 1], v[4 * i + 2], v[4 * i + 3]);
      nr += __shfl_xor(nr, 1); nr += __shfl_xor(nr, 2);
      dt += __shfl_xor(dt, 1); dt += __shfl_xor(dt, 2);
      if ((t & 3) == 0) {
        atomicAdd(&nrmv[rr], nr);
        atomicAdd(&dotv[rr], dt);
      }
    }
  }
}

// Combine split-K partials, layer 0: out = tanh(bias + sum) -> hi/lo.
template <int KS>
__global__ void __launch_bounds__(256)
comb0_hl(const float* __restrict__ P, const float* __restrict__ bias,
         short* __restrict__ Oh, short* __restrict__ Ol, int R, int N) {
  int i = blockIdx.x * 256 + threadIdx.x;
  int n4 = N >> 2;
  int r = i / n4, c4 = (i - r * n4) * 4;
  float4 y = *(const float4*)&P[(size_t)r * N + c4];
  size_t stride = (size_t)R * N;
#pragma unroll
  for (int ks = 1; ks < KS; ++ks) {
    const float4 p = *(const float4*)&P[ks * stride + (size_t)r * N + c4];
    y.x += p.x; y.y += p.y; y.z += p.z; y.w += p.w;
  }
  float4 bc = *(const float4*)(bias + c4);
  float t0 = tanhf(bc.x + y.x), t1 = tanhf(bc.y + y.y);
  float t2 = tanhf(bc.z + y.z), t3 = tanhf(bc.w + y.w);
  short4 h, l;
  h.x = f2bf(t0); l.x = f2bf(t0 - bf2f(h.x));
  h.y = f2bf(t1); l.y = f2bf(t1 - bf2f(h.y));
  h.z = f2bf(t2); l.z = f2bf(t2 - bf2f(h.z));
  h.w = f2bf(t3); l.w = f2bf(t3 - bf2f(h.w));
  *(short4*)&Oh[(size_t)r * N + c4] = h;
  *(short4*)&Ol[(size_t)r * N + c4] = l;
}

// Combine split-K partials, layers 1..3: rows b*Dn+1+2u (tanh(b-y)) and
// b*Dn+2+2u (tanh(b+y)); zero row tanh(b) at u==0. hi/lo out.
template <int KS, int D>
__global__ void __launch_bounds__(256)
comb1_hl(const float* __restrict__ P, const float* __restrict__ bias,
         short* __restrict__ Oh, short* __restrict__ Ol, int R, int N,
         int Dn) {
  int i = blockIdx.x * 256 + threadIdx.x;
  int n4 = N >> 2;
  int r = i / n4, c4 = (i - r * n4) * 4;
  int b = r / D, u = r - b * D;
  float4 y = *(const float4*)&P[(size_t)r * N + c4];
  size_t stride = (size_t)R * N;
#pragma unroll
  for (int ks = 1; ks < KS; ++ks) {
    const float4 p = *(const float4*)&P[ks * stride + (size_t)r * N + c4];
    y.x += p.x; y.y += p.y; y.z += p.z; y.w += p.w;
  }
  float4 bc = *(const float4*)(bias + c4);
  size_t ob = (size_t)(b * Dn) * N + c4;
  size_t om = ob + (size_t)(1 + 2 * u) * N;
  size_t op = ob + (size_t)(2 + 2 * u) * N;
  {
    float t0 = tanhf(bc.x - y.x), t1 = tanhf(bc.y - y.y);
    float t2 = tanhf(bc.z - y.z), t3 = tanhf(bc.w - y.w);
    short4 h, l;
    h.x = f2bf(t0); l.x = f2bf(t0 - bf2f(h.x));
    h.y = f2bf(t1); l.y = f2bf(t1 - bf2f(h.y));
    h.z = f2bf(t2); l.z = f2bf(t2 - bf2f(h.z));
    h.w = f2bf(t3); l.w = f2bf(t3 - bf2f(h.w));
    *(short4*)&Oh[om] = h;
    *(short4*)&Ol[om] = l;
  }
  {
    float t0 = tanhf(bc.x + y.x), t1 = tanhf(bc.y + y.y);
    float t2 = tanhf(bc.z + y.z), t3 = tanhf(bc.w + y.w);
    short4 h, l;
    h.x = f2bf(t0); l.x = f2bf(t0 - bf2f(h.x));
    h.y = f2bf(t1); l.y = f2bf(t1 - bf2f(h.y));
    h.z = f2bf(t2); l.z = f2bf(t2 - bf2f(h.z));
    h.w = f2bf(t3); l.w = f2bf(t3 - bf2f(h.w));
    *(short4*)&Oh[op] = h;
    *(short4*)&Ol[op] = l;
  }
  if (u == 0) {
    float t0 = tanhf(bc.x), t1 = tanhf(bc.y);
    float t2 = tanhf(bc.z), t3 = tanhf(bc.w);
    short4 h, l;
    h.x = f2bf(t0); l.x = f2bf(t0 - bf2f(h.x));
    h.y = f2bf(t1); l.y = f2bf(t1 - bf2f(h.y));
    h.z = f2bf(t2); l.z = f2bf(t2 - bf2f(h.z));
    h.w = f2bf(t3); l.w = f2bf(t3 - bf2f(h.w));
    *(short4*)&Oh[ob] = h;
    *(short4*)&Ol[ob] = l;
  }
}

// Prune after layer 4: 243 entries e = 3*j + t4; class via base-3 digit fold.
__global__ void __launch_bounds__(256)
prune4_k(const float* __restrict__ ns, int* __restrict__ kept4) {
  int b = blockIdx.x, t = threadIdx.x;
  __shared__ float nss[31];
  __shared__ float key[243];
  __shared__ int cls[243];
  if (t < 31) nss[t] = ns[b * 31 + t];
  __syncthreads();
  if (t < 243) {
    int j = t / 3, t4 = t - 3 * j;
    int d0 = j / 27, d1 = (j / 9) % 3, d2 = (j / 3) % 3, d3 = j % 3;
    int u = 0;
    u = (d0 == 1) ? 0 : (1 + 2 * u + (d0 == 2));
    u = (d1 == 1) ? 0 : (1 + 2 * u + (d1 == 2));
    u = (d2 == 1) ? 0 : (1 + 2 * u + (d2 == 2));
    u = (d3 == 1) ? 0 : (1 + 2 * u + (d3 == 2));
    cls[t] = u;
    key[t] = (t4 == 1) ? 0.f : nss[u];
  }
  __syncthreads();
  if (t < 243) {
    float k = key[t];
    int rank = 0;
    for (int e = 0; e < 243; ++e) {
      float ke = key[e];
      rank += (ke > k) || (ke == k && e < t);
    }
    if (rank < 128) {
      int t4 = t - 3 * (t / 3);
      kept4[b * 128 + rank] = (cls[t] << 1) | (t4 == 2 ? 1 : 0);
    }
  }
}

// Final prune 384->128. nb5 computed in-block (deterministic). Keys per
// (class,sign) computed once -> exact ties.
__global__ void __launch_bounds__(384)
prune5_k(const float* __restrict__ dotv, const float* __restrict__ nrmv,
         const float* __restrict__ b5, const int* __restrict__ kept4,
         int* __restrict__ kept5) {
  int b = blockIdx.x, t = threadIdx.x;
  __shared__ float red[384];
  __shared__ float pns[128];
  __shared__ float key[384];
  float p = 0.f;
  for (int o = t; o < 512; o += 384) p = fmaf(b5[o], b5[o], p);
  red[t] = p;
  __syncthreads();
  if (t < 128) red[t] = red[t] + red[t + 128] + red[t + 256];
  __syncthreads();
  if (t < 64) red[t] += red[t + 64];
  __syncthreads();
  if (t < 32) red[t] += red[t + 32];
  __syncthreads();
  if (t < 16) red[t] += red[t + 16];
  __syncthreads();
  if (t < 8) red[t] += red[t + 8];
  __syncthreads();
  if (t < 4) red[t] += red[t + 4];
  __syncthreads();
  if (t < 2) red[t] += red[t + 2];
  __syncthreads();
  if (t == 0) red[0] += red[1];
  __syncthreads();
  float nb5 = red[0];
  if (t < 128) {
    int k4 = kept4[b * 128 + t];
    int c = k4 >> 1;
    float s = (k4 & 1) ? 1.f : -1.f;
    pns[t] = nb5 + nrmv[b * 31 + c] + s * 2.f * dotv[b * 31 + c];
  }
  __syncthreads();
  int m = t / 3, tt = t - 3 * m;
  key[t] = (tt == 1) ? 0.f : pns[m];
  __syncthreads();
  float k = key[t];
  int rank = 0;
  for (int e = 0; e < 384; ++e) {
    float ke = key[e];
    rank += (ke > k) || (ke == k && e < t);
  }
  if (rank < 128) kept5[b * 128 + rank] = (m << 1) | (tt == 2 ? 1 : 0);
}

// Final data (B,512,128) + argmax-|.| output (B,512).
__global__ void __launch_bounds__(256)
finalize_k(const float* __restrict__ Y5, const float* __restrict__ b5,
           const int* __restrict__ kept4, const int* __restrict__ kept5,
           float* __restrict__ out, float* __restrict__ dataout) {
  const int b = blockIdx.y;
  const int o0 = blockIdx.x * 64;
  __shared__ float Ys[31][65];
  __shared__ float bias_s[64];
  __shared__ float vt[64][130];
  __shared__ float ra[64][4];
  __shared__ float rv[64][4];
  const int t = threadIdx.x;
  for (int idx = t; idx < 31 * 64; idx += 256) {
    int c = idx >> 6, o = idx & 63;
    Ys[c][o] = Y5[((size_t)b * 31 + c) * 512 + o0 + o];
  }
  if (t < 64) bias_s[t] = b5[o0 + t];
  const int rr = t & 127, oh = t >> 7;
  int k5 = kept5[b * 128 + rr];
  int m = k5 >> 1;
  float sig = (k5 & 1) ? 1.f : -1.f;
  int k4 = kept4[b * 128 + m];
  int cc = k4 >> 1;
  float s4 = (k4 & 1) ? 1.f : -1.f;
  float afac = sig * s4;
  __syncthreads();
#pragma unroll
  for (int ol = 0; ol < 32; ++ol) {
    int o = oh * 32 + ol;
    float v = sig * bias_s[o] + afac * Ys[cc][o];
    dataout[((size_t)b * 512 + o0 + o) * 128 + rr] = v;
    vt[o][rr] = v;
  }
  __syncthreads();
  int o = t >> 2, q = t & 3;
  float bestv = vt[o][q * 32];
  float besta = fabsf(bestv);
  for (int i = 1; i < 32; ++i) {
    float v = vt[o][q * 32 + i];
    float a = fabsf(v);
    if (a > besta) {
      besta = a;
      bestv = v;
    }
  }
  ra[o][q] = besta;
  rv[o][q] = bestv;
  __syncthreads();
  if (t < 64) {
    float ba = ra[t][0], bv = rv[t][0];
#pragma unroll
    for (int qq = 1; qq < 4; ++qq) {
      if (ra[t][qq] > ba) {
        ba = ra[t][qq];
        bv = rv[t][qq];
      }
    }
    out[(size_t)b * 512 + o0 + t] = bv;
  }
}

extern "C" void kernel_launch(void* const* d_in, const int* in_sizes, int n_in,
                              void* d_out, int out_size, void* d_ws,
                              size_t ws_size, hipStream_t stream) {
  const float* x = (const float*)d_in[0];
  const float* Wt[6];
  const float* bs[6];
  for (int i = 0; i < 6; ++i) {
    Wt[i] = (const float*)d_in[1 + 2 * i];
    bs[i] = (const float*)d_in[2 + 2 * i];
  }
  char* base = (char*)d_ws;
  // Flat layout (~83 MB; ws = 256 MiB per harness fill counters). No aliasing.
  short* A0h = (short*)(base + 0);
  short* A0l = (short*)(base + 262144);
  short* Wh[6], *Wl[6];
  {
    size_t off = 524288;
    for (int i = 0; i < 6; ++i) {
      size_t sz = (i < 5) ? 2097152 : 1048576;
      Wh[i] = (short*)(base + off);
      Wl[i] = (short*)(base + off + sz);
      off += 2 * sz;
    }
  }
  short* C1h = (short*)(base + 23592960), *C1l = (short*)(base + 23855104);
  short* C2h = (short*)(base + 24117248), *C2l = (short*)(base + 24903680);
  short* C3h = (short*)(base + 25690112), *C3l = (short*)(base + 27525120);
  short* C4h = (short*)(base + 29360128), *C4l = (short*)(base + 33292288);
  short* C5h = (short*)(base + 37224448);  // 8126464 B
  short* C5l = (short*)(base + 45350912);
  float* Y5 = (float*)(base + 53477376);   // 8126464 B
  float* PA = (float*)(base + 61603840);   // L0-L2 partials (<=6.3 MB)
  float* PB = (float*)(base + 67895296);   // L3 partials KS=4 (14.68 MB)
  float* ns = (float*)(base + 82575360);   // zone: 12288 floats
  float* dotv = ns + 3968;
  float* nrmv = dotv + 3968;
  int* kept4 = (int*)(base + 82624512);
  int* kept5 = (int*)(base + 82690048);
  float* outp = (float*)d_out;
  float* dataout = outp + 128 * 512;

  dim3 blk(256);
  TWArgs twa;
  for (int i = 0; i < 6; ++i) {
    twa.W[i] = Wt[i];
    twa.Th[i] = Wh[i];
    twa.Tl[i] = Wl[i];
  }
  twa.x = x;
  twa.A0h = A0h;
  twa.A0l = A0l;
  twa.zone = ns;
  transW_all<<<dim3(16, 16, 7), blk, 0, stream>>>(twa);

  // L0: x -> C1 (split-K 8; 256 blocks)
  mfma_gemm_s<8><<<dim3(16, 2, 8), blk, 0, stream>>>(A0h, A0l, Wh[0], Wl[0],
                                                     PA, 1024);
  comb0_hl<8><<<dim3(128), blk, 0, stream>>>(PA, bs[0], C1h, C1l, 128, 1024);
  // L1: C1 -> C2 (split-K 8)
  mfma_gemm_s<8><<<dim3(16, 2, 8), blk, 0, stream>>>(C1h, C1l, Wh[1], Wl[1],
                                                     PA, 1024);
  comb1_hl<8, 1><<<dim3(128), blk, 0, stream>>>(PA, bs[1], C2h, C2l, 128, 1024,
                                                3);
  // L2: C2 (384) -> C3 (split-K 4)
  mfma_gemm_s<4><<<dim3(16, 6, 4), blk, 0, stream>>>(C2h, C2l, Wh[2], Wl[2],
                                                     PA, 1024);
  comb1_hl<4, 3><<<dim3(384), blk, 0, stream>>>(PA, bs[2], C3h, C3l, 384, 1024,
                                                7);
  // L3: C3 (896) -> C4 (big tile, split-K 4 -> 224 blocks)
  mfma_gemm_b<0, 7, 4><<<dim3(8, 7, 4), blk, 0, stream>>>(
      C3h, C3l, Wh[3], Wl[3], nullptr, nullptr, nullptr, PB, nullptr, nullptr,
      nullptr, 1024, 15);
  comb1_hl<4, 7><<<dim3(896), blk, 0, stream>>>(PB, bs[3], C4h, C4l, 896, 1024,
                                                15);
  // L4: C4 (1920) -> C5 (3968) + fused ns sumsq (big tile, 120 blocks)
  mfma_gemm_b<1, 15, 1><<<dim3(8, 15), blk, 0, stream>>>(
      C4h, C4l, Wh[4], Wl[4], bs[4], C5h, C5l, nullptr, ns, nullptr, nullptr,
      1024, 31);
  // Prune 243 -> 128
  prune4_k<<<dim3(128), blk, 0, stream>>>(ns, kept4);
  // L5: C5 -> Y5 raw fp32 (3968 x 512) + fused dot/nrm (big tile, 124 blocks)
  mfma_gemm_b<2, 31, 1><<<dim3(4, 31), blk, 0, stream>>>(
      C5h, C5l, Wh[5], Wl[5], bs[5], nullptr, nullptr, Y5, nullptr, dotv, nrmv,
      512, 0);
  // Final prune + output
  prune5_k<<<dim3(128), dim3(384), 0, stream>>>(dotv, nrmv, bs[5], kept4,
                                                kept5);
  finalize_k<<<dim3(8, 128), blk, 0, stream>>>(Y5, bs[5], kept4, kept5, outp,
                                               dataout);
}